// Round 1
// baseline (2680.225 us; speedup 1.0000x reference)
//
#include <hip/hip_runtime.h>
#include <math.h>

// Problem constants (from reference)
constexpr int Bv = 8;
constexpr int Nv = 4096;      // H*W = 64*64
constexpr int Cvd = 512;
constexpr int Tt = 77;
constexpr int Hh = 8;
constexpr int Dh = 64;
constexpr int MROWS = Bv * Nv;   // 32768
constexpr int KTROWS = Bv * Tt;  // 616

// ---------------------------------------------------------------------------
// LayerNorm (one row of 512 per block, 128 threads), optional gate epilogue
// ---------------------------------------------------------------------------
template<bool GATE>
__global__ __launch_bounds__(128)
void ln_kernel(const float* __restrict__ in, const float* __restrict__ w,
               const float* __restrict__ b, float* __restrict__ out,
               const float* __restrict__ gate_w, const float* __restrict__ gate_b,
               float* __restrict__ gate_out)
{
    __shared__ float red[4];
    __shared__ float redg[2];
    const int row = blockIdx.x;
    const int t = threadIdx.x;          // 0..127, 4 floats each
    const int wv = t >> 6;              // wave id (0,1)
    const float4 v = ((const float4*)(in + (size_t)row * Cvd))[t];

    float s  = v.x + v.y + v.z + v.w;
    float ss = v.x*v.x + v.y*v.y + v.z*v.z + v.w*v.w;
    #pragma unroll
    for (int o = 1; o < 64; o <<= 1) {
        s  += __shfl_xor(s,  o);
        ss += __shfl_xor(ss, o);
    }
    if ((t & 63) == 0) { red[wv*2] = s; red[wv*2+1] = ss; }
    __syncthreads();
    s  = red[0] + red[2];
    ss = red[1] + red[3];
    const float m   = s * (1.0f / 512.0f);
    const float var = ss * (1.0f / 512.0f) - m * m;
    const float rs  = 1.0f / sqrtf(var + 1e-5f);

    const float4 w4 = ((const float4*)w)[t];
    const float4 b4 = ((const float4*)b)[t];
    float4 o4;
    o4.x = (v.x - m) * rs * w4.x + b4.x;
    o4.y = (v.y - m) * rs * w4.y + b4.y;
    o4.z = (v.z - m) * rs * w4.z + b4.z;
    o4.w = (v.w - m) * rs * w4.w + b4.w;
    ((float4*)(out + (size_t)row * Cvd))[t] = o4;

    if (GATE) {
        const float4 g4 = ((const float4*)gate_w)[t];
        float g = o4.x*g4.x + o4.y*g4.y + o4.z*g4.z + o4.w*g4.w;
        #pragma unroll
        for (int o = 1; o < 64; o <<= 1) g += __shfl_xor(g, o);
        if ((t & 63) == 0) redg[wv] = g;
        __syncthreads();
        if (t == 0) {
            const float gt = redg[0] + redg[1] + gate_b[0];
            gate_out[row] = 1.0f / (1.0f + expf(-gt));
        }
    }
}

// ---------------------------------------------------------------------------
// Row L2-norm reciprocal: inv = 1/max(||row||, 1e-6). One wave per row.
// ---------------------------------------------------------------------------
__global__ __launch_bounds__(64)
void rownorm_kernel(const float* __restrict__ src, float* __restrict__ inv)
{
    const int row = blockIdx.x;
    const int l = threadIdx.x;
    const float4* rp = (const float4*)(src + (size_t)row * Cvd);
    const float4 a = rp[l];
    const float4 c = rp[l + 64];
    float ss = a.x*a.x + a.y*a.y + a.z*a.z + a.w*a.w
             + c.x*c.x + c.y*c.y + c.z*c.z + c.w*c.w;
    #pragma unroll
    for (int o = 1; o < 64; o <<= 1) ss += __shfl_xor(ss, o);
    if (l == 0) inv[row] = 1.0f / fmaxf(sqrtf(ss), 1e-6f);
}

// k-norm + pad mask from text features. One wave per text row (616 rows).
__global__ __launch_bounds__(64)
void knorm_mask_kernel(const float* __restrict__ kf, const float* __restrict__ text,
                       float* __restrict__ kinv, float* __restrict__ msk)
{
    const int row = blockIdx.x;
    const int l = threadIdx.x;
    const float4* rp = (const float4*)(kf + (size_t)row * Cvd);
    const float4* tp = (const float4*)(text + (size_t)row * Cvd);
    const float4 a = rp[l], c = rp[l + 64];
    const float4 ta = tp[l], tc = tp[l + 64];
    float ss = a.x*a.x + a.y*a.y + a.z*a.z + a.w*a.w
             + c.x*c.x + c.y*c.y + c.z*c.z + c.w*c.w;
    float sa = fabsf(ta.x)+fabsf(ta.y)+fabsf(ta.z)+fabsf(ta.w)
             + fabsf(tc.x)+fabsf(tc.y)+fabsf(tc.z)+fabsf(tc.w);
    #pragma unroll
    for (int o = 1; o < 64; o <<= 1) {
        ss += __shfl_xor(ss, o);
        sa += __shfl_xor(sa, o);
    }
    if (l == 0) {
        kinv[row] = 1.0f / fmaxf(sqrtf(ss), 1e-6f);
        msk[row]  = (sa <= 1e-6f) ? 1.0f : 0.0f;
    }
}

// ---------------------------------------------------------------------------
// Tiled fp32 GEMM: C[M,N] = epi(A[M,K] @ W[K,N] + bias)
// BM=BN=64, BK=16, 256 threads, 4x4 microtile.
// ---------------------------------------------------------------------------
enum { EPI_NONE = 0, EPI_WO = 1, EPI_GELU = 2, EPI_RES = 3 };

template<int EPI>
__global__ __launch_bounds__(256)
void gemm_kernel(const float* __restrict__ A, int lda,
                 const float* __restrict__ W, int ldw,
                 const float* __restrict__ bias,
                 float* __restrict__ C, int ldc,
                 int M, int K,
                 const float* __restrict__ xres,
                 const float* __restrict__ gate,
                 const float* __restrict__ alpha_p,
                 const float* __restrict__ yres)
{
    __shared__ float As[16][64 + 4];   // transposed [k][m], 16B-aligned rows
    __shared__ float Bs[16][64 + 4];

    const int t = threadIdx.x;
    const int tx = t & 15, ty = t >> 4;
    const int row0 = blockIdx.y * 64;
    const int col0 = blockIdx.x * 64;

    const int arow = t >> 2;           // 0..63
    const int ak   = (t & 3) << 2;     // 0,4,8,12
    const int brow = t >> 4;           // 0..15
    const int bcol = (t & 15) << 2;    // 0..60

    float acc[4][4] = {};

    for (int kt = 0; kt < K; kt += 16) {
        float4 a4 = make_float4(0.f, 0.f, 0.f, 0.f);
        const int gr = row0 + arow;
        if (gr < M) a4 = *(const float4*)(A + (size_t)gr * lda + kt + ak);
        As[ak + 0][arow] = a4.x;
        As[ak + 1][arow] = a4.y;
        As[ak + 2][arow] = a4.z;
        As[ak + 3][arow] = a4.w;
        const float4 b4 = *(const float4*)(W + (size_t)(kt + brow) * ldw + col0 + bcol);
        *(float4*)&Bs[brow][bcol] = b4;
        __syncthreads();
        #pragma unroll
        for (int k = 0; k < 16; k++) {
            const float4 av = *(const float4*)&As[k][ty << 2];
            const float4 bv = *(const float4*)&Bs[k][tx << 2];
            acc[0][0] += av.x * bv.x; acc[0][1] += av.x * bv.y;
            acc[0][2] += av.x * bv.z; acc[0][3] += av.x * bv.w;
            acc[1][0] += av.y * bv.x; acc[1][1] += av.y * bv.y;
            acc[1][2] += av.y * bv.z; acc[1][3] += av.y * bv.w;
            acc[2][0] += av.z * bv.x; acc[2][1] += av.z * bv.y;
            acc[2][2] += av.z * bv.z; acc[2][3] += av.z * bv.w;
            acc[3][0] += av.w * bv.x; acc[3][1] += av.w * bv.y;
            acc[3][2] += av.w * bv.z; acc[3][3] += av.w * bv.w;
        }
        __syncthreads();
    }

    const float alpha = (EPI == EPI_WO) ? alpha_p[0] : 0.0f;
    #pragma unroll
    for (int i = 0; i < 4; i++) {
        const int r = row0 + (ty << 2) + i;
        if (r >= M) continue;
        const float g = (EPI == EPI_WO) ? gate[r] : 0.0f;
        #pragma unroll
        for (int j = 0; j < 4; j++) {
            const int c = col0 + (tx << 2) + j;
            float val = acc[i][j] + bias[c];
            if (EPI == EPI_GELU) val = 0.5f * val * (1.0f + erff(val * 0.70710678118654752f));
            if (EPI == EPI_WO)   val = xres[(size_t)r * ldc + c] + alpha * g * val;
            if (EPI == EPI_RES)  val = yres[(size_t)r * ldc + c] + val;
            C[(size_t)r * ldc + c] = val;
        }
    }
}

// ---------------------------------------------------------------------------
// Attention: per block = (b, h, tile of 256 rows); 256 threads, 4 waves.
// Lane owns one q-row: computes 77 sims, online top-5, softmax, PV.
// ---------------------------------------------------------------------------
__global__ __launch_bounds__(256)
void attn_kernel(const float* __restrict__ qf, const float* __restrict__ kf,
                 const float* __restrict__ vf, const float* __restrict__ qinv,
                 const float* __restrict__ kinv, const float* __restrict__ msk,
                 const float* __restrict__ logit_scale,
                 float* __restrict__ out)
{
    __shared__ float k_lds[Tt][Dh + 4];
    __shared__ float v_lds[Tt][Dh + 4];
    __shared__ float kinv_s[Tt];
    __shared__ float msk_s[Tt];

    const int gid = blockIdx.x;        // (b, h, ntile): b*128 + h*16 + ntile
    const int b = gid >> 7;
    const int h = (gid >> 4) & 7;
    const int ntile = gid & 15;
    const int t = threadIdx.x;

    for (int idx = t; idx < Tt * Dh; idx += 256) {
        const int tt = idx >> 6, dd = idx & 63;
        k_lds[tt][dd] = kf[(size_t)(b * Tt + tt) * Cvd + h * Dh + dd];
        v_lds[tt][dd] = vf[(size_t)(b * Tt + tt) * Cvd + h * Dh + dd];
    }
    if (t < Tt) {
        kinv_s[t] = kinv[b * Tt + t];
        msk_s[t]  = msk[b * Tt + t];
    }
    __syncthreads();

    float ls = logit_scale[0];
    ls = fminf(fmaxf(ls, -2.0f), 2.0f);
    const float scale = expf(ls) * 0.125f;   // / sqrt(64)

    const int wave = t >> 6, lane = t & 63;
    const int row = b * Nv + ntile * 256 + wave * 64 + lane;

    // q row into registers
    float q[Dh];
    const float4* qp = (const float4*)(qf + (size_t)row * Cvd + h * Dh);
    #pragma unroll
    for (int i = 0; i < 16; i++) {
        const float4 x = qp[i];
        q[4*i] = x.x; q[4*i+1] = x.y; q[4*i+2] = x.z; q[4*i+3] = x.w;
    }
    const float qsc = qinv[row] * scale;

    // online top-5 (sorted v0 >= v1 >= ... >= v4)
    float v0 = -INFINITY, v1 = -INFINITY, v2 = -INFINITY, v3 = -INFINITY, v4 = -INFINITY;
    int   i0 = 0, i1 = 0, i2 = 0, i3 = 0, i4 = 0;

    for (int tt = 0; tt < Tt; tt++) {
        float s = 0.0f;
        const float4* kp = (const float4*)&k_lds[tt][0];
        #pragma unroll
        for (int i = 0; i < 16; i++) {
            const float4 kx = kp[i];
            s += q[4*i] * kx.x + q[4*i+1] * kx.y + q[4*i+2] * kx.z + q[4*i+3] * kx.w;
        }
        s = s * qsc * kinv_s[tt];
        if (msk_s[tt] != 0.0f) s = -INFINITY;

        const bool c0 = s > v0, c1 = s > v1, c2 = s > v2, c3 = s > v3, c4 = s > v4;
        const float nv0 = c0 ? s : v0;               const int ni0 = c0 ? tt : i0;
        const float nv1 = c1 ? (c0 ? v0 : s) : v1;   const int ni1 = c1 ? (c0 ? i0 : tt) : i1;
        const float nv2 = c2 ? (c1 ? v1 : s) : v2;   const int ni2 = c2 ? (c1 ? i1 : tt) : i2;
        const float nv3 = c3 ? (c2 ? v2 : s) : v3;   const int ni3 = c3 ? (c2 ? i2 : tt) : i3;
        const float nv4 = c4 ? (c3 ? v3 : s) : v4;   const int ni4 = c4 ? (c3 ? i3 : tt) : i4;
        v0 = nv0; v1 = nv1; v2 = nv2; v3 = nv3; v4 = nv4;
        i0 = ni0; i1 = ni1; i2 = ni2; i3 = ni3; i4 = ni4;
    }

    // softmax over the kept 5
    const float m = v0;
    const float e0 = __expf(v0 - m), e1 = __expf(v1 - m), e2 = __expf(v2 - m),
                e3 = __expf(v3 - m), e4 = __expf(v4 - m);
    const float inv = 1.0f / (e0 + e1 + e2 + e3 + e4);
    const float w0 = e0 * inv, w1 = e1 * inv, w2 = e2 * inv, w3 = e3 * inv, w4 = e4 * inv;

    float* op = out + (size_t)row * Cvd + h * Dh;
    #pragma unroll
    for (int i = 0; i < 16; i++) {
        const float4 p0 = *(const float4*)&v_lds[i0][4*i];
        const float4 p1 = *(const float4*)&v_lds[i1][4*i];
        const float4 p2 = *(const float4*)&v_lds[i2][4*i];
        const float4 p3 = *(const float4*)&v_lds[i3][4*i];
        const float4 p4 = *(const float4*)&v_lds[i4][4*i];
        float4 a;
        a.x = w0*p0.x + w1*p1.x + w2*p2.x + w3*p3.x + w4*p4.x;
        a.y = w0*p0.y + w1*p1.y + w2*p2.y + w3*p3.y + w4*p4.y;
        a.z = w0*p0.z + w1*p1.z + w2*p2.z + w3*p3.z + w4*p4.z;
        a.w = w0*p0.w + w1*p1.w + w2*p2.w + w3*p3.w + w4*p4.w;
        *(float4*)&op[4*i] = a;
    }
}

// ---------------------------------------------------------------------------
extern "C" void kernel_launch(void* const* d_in, const int* in_sizes, int n_in,
                              void* d_out, int out_size, void* d_ws, size_t ws_size,
                              hipStream_t stream)
{
    const float* visual = (const float*)d_in[0];
    const float* text   = (const float*)d_in[1];
    const float* n1w = (const float*)d_in[2];
    const float* n1b = (const float*)d_in[3];
    const float* Wq  = (const float*)d_in[4];
    const float* bq  = (const float*)d_in[5];
    const float* Wk  = (const float*)d_in[6];
    const float* bk  = (const float*)d_in[7];
    const float* Wv  = (const float*)d_in[8];
    const float* bv  = (const float*)d_in[9];
    const float* Wo  = (const float*)d_in[10];
    const float* bo  = (const float*)d_in[11];
    const float* gw  = (const float*)d_in[12];
    const float* gb  = (const float*)d_in[13];
    const float* n2w = (const float*)d_in[14];
    const float* n2b = (const float*)d_in[15];
    const float* w1  = (const float*)d_in[16];
    const float* b1  = (const float*)d_in[17];
    const float* w2  = (const float*)d_in[18];
    const float* b2  = (const float*)d_in[19];
    const float* lsc = (const float*)d_in[20];
    const float* alp = (const float*)d_in[21];

    float* out = (float*)d_out;
    float* ws  = (float*)d_ws;

    // workspace layout (floats): A, B, C big buffers + small arrays
    float* Abuf = ws;                           // 16,777,216
    float* Bbuf = ws + (size_t)16777216;        // 16,777,216
    float* Cbuf = ws + (size_t)2 * 16777216;    // 16,777,216 (ffn hidden chunk)
    float* kf   = ws + (size_t)3 * 16777216;    // 315,392
    float* vf   = kf + 315392;                  // 315,392
    float* qinv = vf + 315392;                  // 32,768
    float* kinv = qinv + 32768;                 // 616
    float* mskp = kinv + 616;                   // 616
    float* gate = mskp + 616;                   // 32,768

    // 1. LN1 + gate logits: x -> d_out (reused later by ffn2 output)
    ln_kernel<true><<<dim3(MROWS), dim3(128), 0, stream>>>(
        visual, n1w, n1b, out, gw, gb, gate);

    // 2. q_full = x @ Wq + bq -> Abuf
    gemm_kernel<EPI_NONE><<<dim3(8, 512), dim3(256), 0, stream>>>(
        out, 512, Wq, 512, bq, Abuf, 512, MROWS, 512,
        nullptr, nullptr, nullptr, nullptr);

    // 3. k_full / v_full from text
    gemm_kernel<EPI_NONE><<<dim3(8, 10), dim3(256), 0, stream>>>(
        text, 512, Wk, 512, bk, kf, 512, KTROWS, 512,
        nullptr, nullptr, nullptr, nullptr);
    gemm_kernel<EPI_NONE><<<dim3(8, 10), dim3(256), 0, stream>>>(
        text, 512, Wv, 512, bv, vf, 512, KTROWS, 512,
        nullptr, nullptr, nullptr, nullptr);

    // 4. row norms + pad mask
    rownorm_kernel<<<dim3(MROWS), dim3(64), 0, stream>>>(Abuf, qinv);
    knorm_mask_kernel<<<dim3(KTROWS), dim3(64), 0, stream>>>(kf, text, kinv, mskp);

    // 5. attention -> Bbuf
    attn_kernel<<<dim3(1024), dim3(256), 0, stream>>>(
        Abuf, kf, vf, qinv, kinv, mskp, lsc, Bbuf);

    // 6. y_pre = x + alpha*gate*(attnout @ Wo + bo) -> Abuf
    gemm_kernel<EPI_WO><<<dim3(8, 512), dim3(256), 0, stream>>>(
        Bbuf, 512, Wo, 512, bo, Abuf, 512, MROWS, 512,
        out, gate, alp, nullptr);

    // 7. y = LN2(y_pre) -> Bbuf
    ln_kernel<false><<<dim3(MROWS), dim3(128), 0, stream>>>(
        Abuf, n2w, n2b, Bbuf, nullptr, nullptr, nullptr);

    // 8. FFN, 4 chunks of 8192 rows: h = gelu(y@w1+b1); out = y + h@w2+b2
    for (int c = 0; c < 4; c++) {
        const float* yA = Bbuf + (size_t)c * 8192 * 512;
        gemm_kernel<EPI_GELU><<<dim3(32, 128), dim3(256), 0, stream>>>(
            yA, 512, w1, 2048, b1, Cbuf, 2048, 8192, 512,
            nullptr, nullptr, nullptr, nullptr);
        gemm_kernel<EPI_RES><<<dim3(8, 128), dim3(256), 0, stream>>>(
            Cbuf, 2048, w2, 512, b2, out + (size_t)c * 8192 * 512, 512, 8192, 2048,
            nullptr, nullptr, nullptr, yA);
    }
}

// Round 3
// 587.123 us; speedup vs baseline: 4.5650x; 4.5650x over previous
//
#include <hip/hip_runtime.h>
#include <hip/hip_bf16.h>
#include <math.h>

// Problem constants (from reference)
constexpr int Bv = 8;
constexpr int Nv = 4096;      // H*W = 64*64
constexpr int Cvd = 512;
constexpr int Tt = 77;
constexpr int Dh = 64;
constexpr int MROWS = Bv * Nv;   // 32768
constexpr int KTROWS = Bv * Tt;  // 616

typedef __attribute__((ext_vector_type(8))) short bf16x8;
typedef __attribute__((ext_vector_type(4))) float f32x4;

// ---------------------------------------------------------------------------
// async global->LDS, 16B per lane. LDS dest must be wave-uniform base;
// HW writes base + lane*16.
// ---------------------------------------------------------------------------
__device__ __forceinline__ void gload16(const void* g, void* l) {
    __builtin_amdgcn_global_load_lds(
        (const __attribute__((address_space(1))) void*)g,
        (__attribute__((address_space(3))) void*)l, 16, 0, 0);
}

// ---------------------------------------------------------------------------
// Weight fp32[K,N] -> bf16[N,K] transpose (32x32 LDS tile, block 32x8=256)
// ---------------------------------------------------------------------------
__global__ __launch_bounds__(256)
void wtrans_kernel(const float* __restrict__ in, __hip_bfloat16* __restrict__ out,
                   int K, int N)
{
    __shared__ float tile[32][33];
    const int n0 = blockIdx.x * 32, k0 = blockIdx.y * 32;
    const int tx = threadIdx.x & 31, ty = threadIdx.x >> 5;
    #pragma unroll
    for (int i = ty; i < 32; i += 8)
        tile[i][tx] = in[(size_t)(k0 + i) * N + n0 + tx];
    __syncthreads();
    #pragma unroll
    for (int i = ty; i < 32; i += 8)
        out[(size_t)(n0 + i) * K + k0 + tx] = __float2bfloat16(tile[tx][i]);
}

// ---------------------------------------------------------------------------
// LayerNorm row of 512, 128 threads; writes f32 + bf16; optional gate logit
// ---------------------------------------------------------------------------
template<bool GATE>
__global__ __launch_bounds__(128)
void ln_kernel(const float* __restrict__ in, const float* __restrict__ w,
               const float* __restrict__ b, float* __restrict__ out,
               __hip_bfloat16* __restrict__ out_bf,
               const float* __restrict__ gate_w, const float* __restrict__ gate_b,
               float* __restrict__ gate_out)
{
    __shared__ float red[4];
    __shared__ float redg[2];
    const int row = blockIdx.x;
    const int t = threadIdx.x;
    const int wv = t >> 6;
    const float4 v = ((const float4*)(in + (size_t)row * Cvd))[t];

    float s  = v.x + v.y + v.z + v.w;
    float ss = v.x*v.x + v.y*v.y + v.z*v.z + v.w*v.w;
    #pragma unroll
    for (int o = 1; o < 64; o <<= 1) {
        s  += __shfl_xor(s,  o);
        ss += __shfl_xor(ss, o);
    }
    if ((t & 63) == 0) { red[wv*2] = s; red[wv*2+1] = ss; }
    __syncthreads();
    s  = red[0] + red[2];
    ss = red[1] + red[3];
    const float m   = s * (1.0f / 512.0f);
    const float var = ss * (1.0f / 512.0f) - m * m;
    const float rs  = 1.0f / sqrtf(var + 1e-5f);

    const float4 w4 = ((const float4*)w)[t];
    const float4 b4 = ((const float4*)b)[t];
    float4 o4;
    o4.x = (v.x - m) * rs * w4.x + b4.x;
    o4.y = (v.y - m) * rs * w4.y + b4.y;
    o4.z = (v.z - m) * rs * w4.z + b4.z;
    o4.w = (v.w - m) * rs * w4.w + b4.w;
    ((float4*)(out + (size_t)row * Cvd))[t] = o4;

    __hip_bfloat162 h0, h1;
    h0.x = __float2bfloat16(o4.x); h0.y = __float2bfloat16(o4.y);
    h1.x = __float2bfloat16(o4.z); h1.y = __float2bfloat16(o4.w);
    __hip_bfloat16* obp = out_bf + (size_t)row * Cvd + 4*t;
    *(__hip_bfloat162*)(obp)     = h0;
    *(__hip_bfloat162*)(obp + 2) = h1;

    if (GATE) {
        const float4 g4 = ((const float4*)gate_w)[t];
        float g = o4.x*g4.x + o4.y*g4.y + o4.z*g4.z + o4.w*g4.w;
        #pragma unroll
        for (int o = 1; o < 64; o <<= 1) g += __shfl_xor(g, o);
        if ((t & 63) == 0) redg[wv] = g;
        __syncthreads();
        if (t == 0) {
            const float gt = redg[0] + redg[1] + gate_b[0];
            gate_out[row] = 1.0f / (1.0f + expf(-gt));
        }
    }
}

// ---------------------------------------------------------------------------
// Row L2-norm reciprocal (fp32 q rows)
// ---------------------------------------------------------------------------
__global__ __launch_bounds__(64)
void rownorm_kernel(const float* __restrict__ src, float* __restrict__ inv)
{
    const int row = blockIdx.x;
    const int l = threadIdx.x;
    const float4* rp = (const float4*)(src + (size_t)row * Cvd);
    const float4 a = rp[l];
    const float4 c = rp[l + 64];
    float ss = a.x*a.x + a.y*a.y + a.z*a.z + a.w*a.w
             + c.x*c.x + c.y*c.y + c.z*c.z + c.w*c.w;
    #pragma unroll
    for (int o = 1; o < 64; o <<= 1) ss += __shfl_xor(ss, o);
    if (l == 0) inv[row] = 1.0f / fmaxf(sqrtf(ss), 1e-6f);
}

__global__ __launch_bounds__(64)
void knorm_mask_kernel(const float* __restrict__ kf, const float* __restrict__ text,
                       float* __restrict__ kinv, float* __restrict__ msk)
{
    const int row = blockIdx.x;
    const int l = threadIdx.x;
    const float4* rp = (const float4*)(kf + (size_t)row * Cvd);
    const float4* tp = (const float4*)(text + (size_t)row * Cvd);
    const float4 a = rp[l], c = rp[l + 64];
    const float4 ta = tp[l], tc = tp[l + 64];
    float ss = a.x*a.x + a.y*a.y + a.z*a.z + a.w*a.w
             + c.x*c.x + c.y*c.y + c.z*c.z + c.w*c.w;
    float sa = fabsf(ta.x)+fabsf(ta.y)+fabsf(ta.z)+fabsf(ta.w)
             + fabsf(tc.x)+fabsf(tc.y)+fabsf(tc.z)+fabsf(tc.w);
    #pragma unroll
    for (int o = 1; o < 64; o <<= 1) {
        ss += __shfl_xor(ss, o);
        sa += __shfl_xor(sa, o);
    }
    if (l == 0) {
        kinv[row] = 1.0f / fmaxf(sqrtf(ss), 1e-6f);
        msk[row]  = (sa <= 1e-6f) ? 1.0f : 0.0f;
    }
}

// ---------------------------------------------------------------------------
// fp32 tiled GEMM (kept only for tiny k/v projections, M=616)
// ---------------------------------------------------------------------------
__global__ __launch_bounds__(256)
void gemm32_kernel(const float* __restrict__ A, int lda,
                   const float* __restrict__ W, int ldw,
                   const float* __restrict__ bias,
                   float* __restrict__ C, int ldc,
                   int M, int K)
{
    __shared__ float As[16][64 + 4];
    __shared__ float Bs[16][64 + 4];

    const int t = threadIdx.x;
    const int tx = t & 15, ty = t >> 4;
    const int row0 = blockIdx.y * 64;
    const int col0 = blockIdx.x * 64;

    const int arow = t >> 2;
    const int ak   = (t & 3) << 2;
    const int brow = t >> 4;
    const int bcol = (t & 15) << 2;

    float acc[4][4] = {};

    for (int kt = 0; kt < K; kt += 16) {
        float4 a4 = make_float4(0.f, 0.f, 0.f, 0.f);
        const int gr = row0 + arow;
        if (gr < M) a4 = *(const float4*)(A + (size_t)gr * lda + kt + ak);
        As[ak + 0][arow] = a4.x;
        As[ak + 1][arow] = a4.y;
        As[ak + 2][arow] = a4.z;
        As[ak + 3][arow] = a4.w;
        const float4 b4 = *(const float4*)(W + (size_t)(kt + brow) * ldw + col0 + bcol);
        *(float4*)&Bs[brow][bcol] = b4;
        __syncthreads();
        #pragma unroll
        for (int k = 0; k < 16; k++) {
            const float4 av = *(const float4*)&As[k][ty << 2];
            const float4 bv = *(const float4*)&Bs[k][tx << 2];
            acc[0][0] += av.x * bv.x; acc[0][1] += av.x * bv.y;
            acc[0][2] += av.x * bv.z; acc[0][3] += av.x * bv.w;
            acc[1][0] += av.y * bv.x; acc[1][1] += av.y * bv.y;
            acc[1][2] += av.y * bv.z; acc[1][3] += av.y * bv.w;
            acc[2][0] += av.z * bv.x; acc[2][1] += av.z * bv.y;
            acc[2][2] += av.z * bv.z; acc[2][3] += av.z * bv.w;
            acc[3][0] += av.w * bv.x; acc[3][1] += av.w * bv.y;
            acc[3][2] += av.w * bv.z; acc[3][3] += av.w * bv.w;
        }
        __syncthreads();
    }

    #pragma unroll
    for (int i = 0; i < 4; i++) {
        const int r = row0 + (ty << 2) + i;
        if (r >= M) continue;
        #pragma unroll
        for (int j = 0; j < 4; j++) {
            const int c = col0 + (tx << 2) + j;
            C[(size_t)r * ldc + c] = acc[i][j] + bias[c];
        }
    }
}

// ---------------------------------------------------------------------------
// bf16 MFMA GEMM (m97 structure): C[M,N] = epi(A[M,K] @ Bt[N,K]^T + bias)
// BM=BN=128, BK=32, 256 threads (4 waves, 2x2), 4x4 16x16 frags per wave.
// A, Bt bf16 row-major; M,N %128==0, K %32==0. Staging via global_load_lds.
// ---------------------------------------------------------------------------
enum { EPI_NONE = 0, EPI_WO = 1, EPI_GELU = 2, EPI_RES = 3 };

template<int EPI>
__global__ __launch_bounds__(256)
void bgemm_kernel(const __hip_bfloat16* __restrict__ Ah,
                  const __hip_bfloat16* __restrict__ Bth,
                  const float* __restrict__ bias,
                  void* __restrict__ Cout,
                  int M, int N, int K,
                  const float* __restrict__ xres,
                  const float* __restrict__ gate,
                  const float* __restrict__ alpha_p,
                  const float* __restrict__ yres)
{
    __shared__ short As[128 * 32];   // [row][k] row-major, 64B rows
    __shared__ short Bs[128 * 32];   // [col][k] row-major (Bt rows)

    const short* A  = (const short*)Ah;
    const short* Bt = (const short*)Bth;

    const int t = threadIdx.x;
    const int w = t >> 6, l = t & 63;
    const int wr = w >> 1, wc = w & 1;
    const int row0 = blockIdx.y * 128;
    const int col0 = blockIdx.x * 128;

    // staging: chunk c covers 16 rows (1 KB); wave w stages chunks 2w, 2w+1
    const int c0 = w * 2, c1 = w * 2 + 1;
    const int srow = l >> 2;            // 0..15 within chunk
    const int skc  = (l & 3) * 8;       // k element base of the 16B
    const short* gA0 = A  + (size_t)(row0 + 16*c0 + srow) * K + skc;
    const short* gA1 = A  + (size_t)(row0 + 16*c1 + srow) * K + skc;
    const short* gB0 = Bt + (size_t)(col0 + 16*c0 + srow) * K + skc;
    const short* gB1 = Bt + (size_t)(col0 + 16*c1 + srow) * K + skc;
    short* lA0 = As + c0 * 512;         // wave-uniform LDS bases
    short* lA1 = As + c1 * 512;
    short* lB0 = Bs + c0 * 512;
    short* lB1 = Bs + c1 * 512;

    // fragment read offsets (elements), k-invariant
    int aoff[4], boff[4];
    #pragma unroll
    for (int mi = 0; mi < 4; mi++)
        aoff[mi] = (wr*64 + mi*16 + (l & 15)) * 32 + (l >> 4) * 8;
    #pragma unroll
    for (int ni = 0; ni < 4; ni++)
        boff[ni] = (wc*64 + ni*16 + (l & 15)) * 32 + (l >> 4) * 8;

    f32x4 acc[4][4] = {};

    for (int kt = 0; kt < K; kt += 32) {
        gload16(gA0, lA0); gload16(gA1, lA1);
        gload16(gB0, lB0); gload16(gB1, lB1);
        gA0 += 32; gA1 += 32; gB0 += 32; gB1 += 32;
        __syncthreads();                 // compiler drains vmcnt before barrier

        bf16x8 af[4], bfr[4];
        #pragma unroll
        for (int mi = 0; mi < 4; mi++) af[mi]  = *(const bf16x8*)(As + aoff[mi]);
        #pragma unroll
        for (int ni = 0; ni < 4; ni++) bfr[ni] = *(const bf16x8*)(Bs + boff[ni]);
        #pragma unroll
        for (int mi = 0; mi < 4; mi++)
            #pragma unroll
            for (int ni = 0; ni < 4; ni++)
                acc[mi][ni] = __builtin_amdgcn_mfma_f32_16x16x32_bf16(
                    af[mi], bfr[ni], acc[mi][ni], 0, 0, 0);
        __syncthreads();
    }

    const float alpha = (EPI == EPI_WO) ? alpha_p[0] : 0.0f;
    #pragma unroll
    for (int mi = 0; mi < 4; mi++) {
        const int rbase = row0 + wr*64 + mi*16 + ((l >> 4) << 2);
        #pragma unroll
        for (int ni = 0; ni < 4; ni++) {
            const int c = col0 + wc*64 + ni*16 + (l & 15);
            const float bc = bias[c];
            #pragma unroll
            for (int r = 0; r < 4; r++) {
                const int rr = rbase + r;
                const size_t idx = (size_t)rr * N + c;
                float val = acc[mi][ni][r] + bc;
                if (EPI == EPI_GELU) {
                    val = 0.5f * val * (1.0f + erff(val * 0.70710678118654752f));
                    ((__hip_bfloat16*)Cout)[idx] = __float2bfloat16(val);
                } else if (EPI == EPI_WO) {
                    ((float*)Cout)[idx] = xres[idx] + alpha * gate[rr] * val;
                } else if (EPI == EPI_RES) {
                    ((float*)Cout)[idx] = yres[idx] + val;
                } else {
                    ((float*)Cout)[idx] = val;
                }
            }
        }
    }
}

// ---------------------------------------------------------------------------
// Attention (fp32 math): block = (b, h, 256-row tile); lane owns one q row.
// top-5 online, softmax over 5, PV. Output bf16.
// ---------------------------------------------------------------------------
__global__ __launch_bounds__(256)
void attn_kernel(const float* __restrict__ qf, const float* __restrict__ kf,
                 const float* __restrict__ vf, const float* __restrict__ qinv,
                 const float* __restrict__ kinv, const float* __restrict__ msk,
                 const float* __restrict__ logit_scale,
                 __hip_bfloat16* __restrict__ out)
{
    __shared__ float k_lds[Tt][Dh + 4];
    __shared__ float v_lds[Tt][Dh + 4];
    __shared__ float kinv_s[Tt];
    __shared__ float msk_s[Tt];

    const int gid = blockIdx.x;
    const int b = gid >> 7;
    const int h = (gid >> 4) & 7;
    const int ntile = gid & 15;
    const int t = threadIdx.x;

    for (int idx = t; idx < Tt * Dh; idx += 256) {
        const int tt = idx >> 6, dd = idx & 63;
        k_lds[tt][dd] = kf[(size_t)(b * Tt + tt) * Cvd + h * Dh + dd];
        v_lds[tt][dd] = vf[(size_t)(b * Tt + tt) * Cvd + h * Dh + dd];
    }
    if (t < Tt) {
        kinv_s[t] = kinv[b * Tt + t];
        msk_s[t]  = msk[b * Tt + t];
    }
    __syncthreads();

    float ls = logit_scale[0];
    ls = fminf(fmaxf(ls, -2.0f), 2.0f);
    const float scale = expf(ls) * 0.125f;

    const int wave = t >> 6, lane = t & 63;
    const int row = b * Nv + ntile * 256 + wave * 64 + lane;

    float q[Dh];
    const float4* qp = (const float4*)(qf + (size_t)row * Cvd + h * Dh);
    #pragma unroll
    for (int i = 0; i < 16; i++) {
        const float4 x = qp[i];
        q[4*i] = x.x; q[4*i+1] = x.y; q[4*i+2] = x.z; q[4*i+3] = x.w;
    }
    const float qsc = qinv[row] * scale;

    float v0 = -INFINITY, v1 = -INFINITY, v2 = -INFINITY, v3 = -INFINITY, v4 = -INFINITY;
    int   i0 = 0, i1 = 0, i2 = 0, i3 = 0, i4 = 0;

    for (int tt = 0; tt < Tt; tt++) {
        float s = 0.0f;
        const float4* kp = (const float4*)&k_lds[tt][0];
        #pragma unroll
        for (int i = 0; i < 16; i++) {
            const float4 kx = kp[i];
            s += q[4*i] * kx.x + q[4*i+1] * kx.y + q[4*i+2] * kx.z + q[4*i+3] * kx.w;
        }
        s = s * qsc * kinv_s[tt];
        if (msk_s[tt] != 0.0f) s = -INFINITY;

        const bool c0 = s > v0, c1 = s > v1, c2 = s > v2, c3 = s > v3, c4 = s > v4;
        const float nv0 = c0 ? s : v0;               const int ni0 = c0 ? tt : i0;
        const float nv1 = c1 ? (c0 ? v0 : s) : v1;   const int ni1 = c1 ? (c0 ? i0 : tt) : i1;
        const float nv2 = c2 ? (c1 ? v1 : s) : v2;   const int ni2 = c2 ? (c1 ? i1 : tt) : i2;
        const float nv3 = c3 ? (c2 ? v2 : s) : v3;   const int ni3 = c3 ? (c2 ? i2 : tt) : i3;
        const float nv4 = c4 ? (c3 ? v3 : s) : v4;   const int ni4 = c4 ? (c3 ? i3 : tt) : i4;
        v0 = nv0; v1 = nv1; v2 = nv2; v3 = nv3; v4 = nv4;
        i0 = ni0; i1 = ni1; i2 = ni2; i3 = ni3; i4 = ni4;
    }

    const float m = v0;
    const float e0 = __expf(v0 - m), e1 = __expf(v1 - m), e2 = __expf(v2 - m),
                e3 = __expf(v3 - m), e4 = __expf(v4 - m);
    const float inv = 1.0f / (e0 + e1 + e2 + e3 + e4);
    const float w0 = e0 * inv, w1 = e1 * inv, w2 = e2 * inv, w3 = e3 * inv, w4 = e4 * inv;

    __hip_bfloat16* op = out + (size_t)row * Cvd + h * Dh;
    #pragma unroll
    for (int i = 0; i < 16; i++) {
        const float4 p0 = *(const float4*)&v_lds[i0][4*i];
        const float4 p1 = *(const float4*)&v_lds[i1][4*i];
        const float4 p2 = *(const float4*)&v_lds[i2][4*i];
        const float4 p3 = *(const float4*)&v_lds[i3][4*i];
        const float4 p4 = *(const float4*)&v_lds[i4][4*i];
        float4 a;
        a.x = w0*p0.x + w1*p1.x + w2*p2.x + w3*p3.x + w4*p4.x;
        a.y = w0*p0.y + w1*p1.y + w2*p2.y + w3*p3.y + w4*p4.y;
        a.z = w0*p0.z + w1*p1.z + w2*p2.z + w3*p3.z + w4*p4.z;
        a.w = w0*p0.w + w1*p1.w + w2*p2.w + w3*p3.w + w4*p4.w;
        __hip_bfloat162 h0, h1;
        h0.x = __float2bfloat16(a.x); h0.y = __float2bfloat16(a.y);
        h1.x = __float2bfloat16(a.z); h1.y = __float2bfloat16(a.w);
        *(__hip_bfloat162*)&op[4*i]     = h0;
        *(__hip_bfloat162*)&op[4*i + 2] = h1;
    }
}

// ---------------------------------------------------------------------------
extern "C" void kernel_launch(void* const* d_in, const int* in_sizes, int n_in,
                              void* d_out, int out_size, void* d_ws, size_t ws_size,
                              hipStream_t stream)
{
    const float* visual = (const float*)d_in[0];
    const float* text   = (const float*)d_in[1];
    const float* n1w = (const float*)d_in[2];
    const float* n1b = (const float*)d_in[3];
    const float* Wq  = (const float*)d_in[4];
    const float* bq  = (const float*)d_in[5];
    const float* Wk  = (const float*)d_in[6];
    const float* bk  = (const float*)d_in[7];
    const float* Wv  = (const float*)d_in[8];
    const float* bv  = (const float*)d_in[9];
    const float* Wo  = (const float*)d_in[10];
    const float* bo  = (const float*)d_in[11];
    const float* gw  = (const float*)d_in[12];
    const float* gb  = (const float*)d_in[13];
    const float* n2w = (const float*)d_in[14];
    const float* n2b = (const float*)d_in[15];
    const float* w1  = (const float*)d_in[16];
    const float* b1  = (const float*)d_in[17];
    const float* w2  = (const float*)d_in[18];
    const float* b2  = (const float*)d_in[19];
    const float* lsc = (const float*)d_in[20];
    const float* alp = (const float*)d_in[21];

    float* out = (float*)d_out;
    char*  w8  = (char*)d_ws;

    // workspace (byte offsets, aliased by lifetime):
    // [0,64Mi)    q_full f32            (steps 2..5)   \ aliased by
    // [64Mi,128Mi) y_pre f32            (steps 6..7)   / hidden bf16 (step 8+)
    // [128Mi,160Mi) x_bf16 / attnout_bf16 / y_bf16 (sequential lifetimes)
    float*          qfull  = (float*)(w8 + 0);
    float*          ypre   = (float*)(w8 + 67108864);
    __hip_bfloat16* hidden = (__hip_bfloat16*)(w8 + 0);
    __hip_bfloat16* xbf    = (__hip_bfloat16*)(w8 + 134217728);  // also attnout, y_bf16
    float*          kf     = (float*)(w8 + 167772160);
    float*          vf     = (float*)(w8 + 169033728);
    float*          qinv   = (float*)(w8 + 170295296);
    float*          kinv   = (float*)(w8 + 170426368);
    float*          mskp   = (float*)(w8 + 170428832);
    float*          gate   = (float*)(w8 + 170431296);
    __hip_bfloat16* WqT    = (__hip_bfloat16*)(w8 + 170562368);
    __hip_bfloat16* WoT    = (__hip_bfloat16*)(w8 + 171086656);
    __hip_bfloat16* w1T    = (__hip_bfloat16*)(w8 + 171610944);
    __hip_bfloat16* w2T    = (__hip_bfloat16*)(w8 + 173708096);

    // 0. weights -> bf16 transposed [N,K]
    wtrans_kernel<<<dim3(16, 16), dim3(256), 0, stream>>>(Wq, WqT, 512, 512);
    wtrans_kernel<<<dim3(16, 16), dim3(256), 0, stream>>>(Wo, WoT, 512, 512);
    wtrans_kernel<<<dim3(64, 16), dim3(256), 0, stream>>>(w1, w1T, 512, 2048);
    wtrans_kernel<<<dim3(16, 64), dim3(256), 0, stream>>>(w2, w2T, 2048, 512);

    // 1. LN1: x -> d_out (f32) + xbf (bf16); gate logits
    ln_kernel<true><<<dim3(MROWS), dim3(128), 0, stream>>>(
        visual, n1w, n1b, out, xbf, gw, gb, gate);

    // 2. q_full = x @ Wq + bq  (bf16 MFMA, f32 out)
    bgemm_kernel<EPI_NONE><<<dim3(4, 256), dim3(256), 0, stream>>>(
        xbf, WqT, bq, qfull, MROWS, 512, 512, nullptr, nullptr, nullptr, nullptr);

    // 3. k_full / v_full (fp32, tiny M=616)
    gemm32_kernel<<<dim3(8, 10), dim3(256), 0, stream>>>(
        text, 512, Wk, 512, bk, kf, 512, KTROWS, 512);
    gemm32_kernel<<<dim3(8, 10), dim3(256), 0, stream>>>(
        text, 512, Wv, 512, bv, vf, 512, KTROWS, 512);

    // 4. norms + pad mask
    rownorm_kernel<<<dim3(MROWS), dim3(64), 0, stream>>>(qfull, qinv);
    knorm_mask_kernel<<<dim3(KTROWS), dim3(64), 0, stream>>>(kf, text, kinv, mskp);

    // 5. attention -> attnout bf16 (reuses xbf buffer; x_bf16 dead)
    attn_kernel<<<dim3(1024), dim3(256), 0, stream>>>(
        qfull, kf, vf, qinv, kinv, mskp, lsc, xbf);

    // 6. y_pre = x + alpha*gate*(attnout @ Wo + bo)
    bgemm_kernel<EPI_WO><<<dim3(4, 256), dim3(256), 0, stream>>>(
        xbf, WoT, bo, ypre, MROWS, 512, 512, out, gate, alp, nullptr);

    // 7. y = LN2(y_pre) -> d_out (f32, residual for FFN2) + y_bf16 (reuses xbf)
    ln_kernel<false><<<dim3(MROWS), dim3(128), 0, stream>>>(
        ypre, n2w, n2b, out, xbf, nullptr, nullptr, nullptr);

    // 8. hidden = gelu(y @ w1 + b1) -> bf16 (aliases qfull+ypre, both dead)
    bgemm_kernel<EPI_GELU><<<dim3(16, 256), dim3(256), 0, stream>>>(
        xbf, w1T, b1, hidden, MROWS, 2048, 512, nullptr, nullptr, nullptr, nullptr);

    // 9. out = y + hidden @ w2 + b2 (in-place on d_out)
    bgemm_kernel<EPI_RES><<<dim3(4, 256), dim3(256), 0, stream>>>(
        hidden, w2T, b2, out, MROWS, 512, 2048, nullptr, nullptr, nullptr, out);
}

// Round 4
// 522.116 us; speedup vs baseline: 5.1334x; 1.1245x over previous
//
#include <hip/hip_runtime.h>
#include <hip/hip_bf16.h>
#include <math.h>

// Problem constants (from reference)
constexpr int Bv = 8;
constexpr int Nv = 4096;      // H*W = 64*64
constexpr int Cvd = 512;
constexpr int Tt = 77;
constexpr int Dh = 64;
constexpr int MROWS = Bv * Nv;   // 32768
constexpr int KTROWS = Bv * Tt;  // 616

typedef __attribute__((ext_vector_type(8))) short bf16x8;
typedef __attribute__((ext_vector_type(4))) float f32x4;

// ---------------------------------------------------------------------------
// async global->LDS, 16B per lane. LDS dest wave-uniform base; HW adds lane*16.
// ---------------------------------------------------------------------------
__device__ __forceinline__ void gload16(const void* g, void* l) {
    __builtin_amdgcn_global_load_lds(
        (const __attribute__((address_space(1))) void*)g,
        (__attribute__((address_space(3))) void*)l, 16, 0, 0);
}

// raw barrier with compiler memory fences (NO vmcnt drain — that is the point)
__device__ __forceinline__ void block_barrier() {
    asm volatile("" ::: "memory");
    __builtin_amdgcn_s_barrier();
    asm volatile("" ::: "memory");
}

// ---------------------------------------------------------------------------
// Weight fp32[K,N] -> bf16[N,K] transpose (32x32 LDS tile, block 32x8=256)
// ---------------------------------------------------------------------------
__global__ __launch_bounds__(256)
void wtrans_kernel(const float* __restrict__ in, __hip_bfloat16* __restrict__ out,
                   int K, int N)
{
    __shared__ float tile[32][33];
    const int n0 = blockIdx.x * 32, k0 = blockIdx.y * 32;
    const int tx = threadIdx.x & 31, ty = threadIdx.x >> 5;
    #pragma unroll
    for (int i = ty; i < 32; i += 8)
        tile[i][tx] = in[(size_t)(k0 + i) * N + n0 + tx];
    __syncthreads();
    #pragma unroll
    for (int i = ty; i < 32; i += 8)
        out[(size_t)(n0 + i) * K + k0 + tx] = __float2bfloat16(tile[tx][i]);
}

// ---------------------------------------------------------------------------
// LayerNorm row of 512, 128 threads; writes f32 + bf16; optional gate logit
// ---------------------------------------------------------------------------
template<bool GATE>
__global__ __launch_bounds__(128)
void ln_kernel(const float* __restrict__ in, const float* __restrict__ w,
               const float* __restrict__ b, float* __restrict__ out,
               __hip_bfloat16* __restrict__ out_bf,
               const float* __restrict__ gate_w, const float* __restrict__ gate_b,
               float* __restrict__ gate_out)
{
    __shared__ float red[4];
    __shared__ float redg[2];
    const int row = blockIdx.x;
    const int t = threadIdx.x;
    const int wv = t >> 6;
    const float4 v = ((const float4*)(in + (size_t)row * Cvd))[t];

    float s  = v.x + v.y + v.z + v.w;
    float ss = v.x*v.x + v.y*v.y + v.z*v.z + v.w*v.w;
    #pragma unroll
    for (int o = 1; o < 64; o <<= 1) {
        s  += __shfl_xor(s,  o);
        ss += __shfl_xor(ss, o);
    }
    if ((t & 63) == 0) { red[wv*2] = s; red[wv*2+1] = ss; }
    __syncthreads();
    s  = red[0] + red[2];
    ss = red[1] + red[3];
    const float m   = s * (1.0f / 512.0f);
    const float var = ss * (1.0f / 512.0f) - m * m;
    const float rs  = 1.0f / sqrtf(var + 1e-5f);

    const float4 w4 = ((const float4*)w)[t];
    const float4 b4 = ((const float4*)b)[t];
    float4 o4;
    o4.x = (v.x - m) * rs * w4.x + b4.x;
    o4.y = (v.y - m) * rs * w4.y + b4.y;
    o4.z = (v.z - m) * rs * w4.z + b4.z;
    o4.w = (v.w - m) * rs * w4.w + b4.w;
    ((float4*)(out + (size_t)row * Cvd))[t] = o4;

    __hip_bfloat162 h0, h1;
    h0.x = __float2bfloat16(o4.x); h0.y = __float2bfloat16(o4.y);
    h1.x = __float2bfloat16(o4.z); h1.y = __float2bfloat16(o4.w);
    __hip_bfloat16* obp = out_bf + (size_t)row * Cvd + 4*t;
    *(__hip_bfloat162*)(obp)     = h0;
    *(__hip_bfloat162*)(obp + 2) = h1;

    if (GATE) {
        const float4 g4 = ((const float4*)gate_w)[t];
        float g = o4.x*g4.x + o4.y*g4.y + o4.z*g4.z + o4.w*g4.w;
        #pragma unroll
        for (int o = 1; o < 64; o <<= 1) g += __shfl_xor(g, o);
        if ((t & 63) == 0) redg[wv] = g;
        __syncthreads();
        if (t == 0) {
            const float gt = redg[0] + redg[1] + gate_b[0];
            gate_out[row] = 1.0f / (1.0f + expf(-gt));
        }
    }
}

// ---------------------------------------------------------------------------
// Row L2-norm reciprocal (fp32 q rows)
// ---------------------------------------------------------------------------
__global__ __launch_bounds__(64)
void rownorm_kernel(const float* __restrict__ src, float* __restrict__ inv)
{
    const int row = blockIdx.x;
    const int l = threadIdx.x;
    const float4* rp = (const float4*)(src + (size_t)row * Cvd);
    const float4 a = rp[l];
    const float4 c = rp[l + 64];
    float ss = a.x*a.x + a.y*a.y + a.z*a.z + a.w*a.w
             + c.x*c.x + c.y*c.y + c.z*c.z + c.w*c.w;
    #pragma unroll
    for (int o = 1; o < 64; o <<= 1) ss += __shfl_xor(ss, o);
    if (l == 0) inv[row] = 1.0f / fmaxf(sqrtf(ss), 1e-6f);
}

__global__ __launch_bounds__(64)
void knorm_mask_kernel(const float* __restrict__ kf, const float* __restrict__ text,
                       float* __restrict__ kinv, float* __restrict__ msk)
{
    const int row = blockIdx.x;
    const int l = threadIdx.x;
    const float4* rp = (const float4*)(kf + (size_t)row * Cvd);
    const float4* tp = (const float4*)(text + (size_t)row * Cvd);
    const float4 a = rp[l], c = rp[l + 64];
    const float4 ta = tp[l], tc = tp[l + 64];
    float ss = a.x*a.x + a.y*a.y + a.z*a.z + a.w*a.w
             + c.x*c.x + c.y*c.y + c.z*c.z + c.w*c.w;
    float sa = fabsf(ta.x)+fabsf(ta.y)+fabsf(ta.z)+fabsf(ta.w)
             + fabsf(tc.x)+fabsf(tc.y)+fabsf(tc.z)+fabsf(tc.w);
    #pragma unroll
    for (int o = 1; o < 64; o <<= 1) {
        ss += __shfl_xor(ss, o);
        sa += __shfl_xor(sa, o);
    }
    if (l == 0) {
        kinv[row] = 1.0f / fmaxf(sqrtf(ss), 1e-6f);
        msk[row]  = (sa <= 1e-6f) ? 1.0f : 0.0f;
    }
}

// ---------------------------------------------------------------------------
// fp32 tiled GEMM (tiny k/v projections, M=616)
// ---------------------------------------------------------------------------
__global__ __launch_bounds__(256)
void gemm32_kernel(const float* __restrict__ A, int lda,
                   const float* __restrict__ W, int ldw,
                   const float* __restrict__ bias,
                   float* __restrict__ C, int ldc,
                   int M, int K)
{
    __shared__ float As[16][64 + 4];
    __shared__ float Bs[16][64 + 4];

    const int t = threadIdx.x;
    const int tx = t & 15, ty = t >> 4;
    const int row0 = blockIdx.y * 64;
    const int col0 = blockIdx.x * 64;

    const int arow = t >> 2;
    const int ak   = (t & 3) << 2;
    const int brow = t >> 4;
    const int bcol = (t & 15) << 2;

    float acc[4][4] = {};

    for (int kt = 0; kt < K; kt += 16) {
        float4 a4 = make_float4(0.f, 0.f, 0.f, 0.f);
        const int gr = row0 + arow;
        if (gr < M) a4 = *(const float4*)(A + (size_t)gr * lda + kt + ak);
        As[ak + 0][arow] = a4.x;
        As[ak + 1][arow] = a4.y;
        As[ak + 2][arow] = a4.z;
        As[ak + 3][arow] = a4.w;
        const float4 b4 = *(const float4*)(W + (size_t)(kt + brow) * ldw + col0 + bcol);
        *(float4*)&Bs[brow][bcol] = b4;
        __syncthreads();
        #pragma unroll
        for (int k = 0; k < 16; k++) {
            const float4 av = *(const float4*)&As[k][ty << 2];
            const float4 bv = *(const float4*)&Bs[k][tx << 2];
            acc[0][0] += av.x * bv.x; acc[0][1] += av.x * bv.y;
            acc[0][2] += av.x * bv.z; acc[0][3] += av.x * bv.w;
            acc[1][0] += av.y * bv.x; acc[1][1] += av.y * bv.y;
            acc[1][2] += av.y * bv.z; acc[1][3] += av.y * bv.w;
            acc[2][0] += av.z * bv.x; acc[2][1] += av.z * bv.y;
            acc[2][2] += av.z * bv.z; acc[2][3] += av.z * bv.w;
            acc[3][0] += av.w * bv.x; acc[3][1] += av.w * bv.y;
            acc[3][2] += av.w * bv.z; acc[3][3] += av.w * bv.w;
        }
        __syncthreads();
    }

    #pragma unroll
    for (int i = 0; i < 4; i++) {
        const int r = row0 + (ty << 2) + i;
        if (r >= M) continue;
        #pragma unroll
        for (int j = 0; j < 4; j++) {
            const int c = col0 + (tx << 2) + j;
            C[(size_t)r * ldc + c] = acc[i][j] + bias[c];
        }
    }
}

// ---------------------------------------------------------------------------
// bf16 MFMA GEMM, 256x256 tile, BK=64, 512 threads (8 waves, 2Mx4N),
// 8-phase counted-vmcnt schedule (T2 swizzle + T3/T4 + T5 setprio).
// C[M,N] = epi(A[M,K] @ Bt[N,K]^T + bias). M,N %256==0, K %64==0.
//
// LDS: 2 buffers x {A_k0, A_k1, B_k0, B_k1} halves of 16KB = 128 KiB.
// Stage stream: one half per phase, 2 global_load_lds per wave per stage.
// vmcnt(6) at kh boundaries = 3 half-tiles in flight, never drained in loop.
// T2: 16B-granule XOR swizzle byte^=((r>>1)&3)<<4, applied as pre-swizzled
// global source (linear LDS dest, rule #21) + swizzled ds_read address.
// ---------------------------------------------------------------------------
enum { EPI_NONE = 0, EPI_WO = 1, EPI_GELU = 2, EPI_RES = 3 };

template<int EPI>
__global__ __launch_bounds__(512, 2)
void bgemm8_kernel(const __hip_bfloat16* __restrict__ Ah,
                   const __hip_bfloat16* __restrict__ Bth,
                   const float* __restrict__ bias,
                   void* __restrict__ Cout,
                   int M, int N, int K,
                   const float* __restrict__ xres,
                   const float* __restrict__ gate,
                   const float* __restrict__ alpha_p,
                   const float* __restrict__ yres)
{
    __shared__ short lds[65536];   // 128 KiB

    const short* A  = (const short*)Ah;
    const short* Bt = (const short*)Bth;

    // XCD-aware bijective swizzle (nwg % 8 == 0 for all our shapes)
    const int nwg = gridDim.x;
    const int cpx = nwg >> 3;
    const int bid0 = blockIdx.x;
    const int bid = (bid0 & 7) * cpx + (bid0 >> 3);
    const int cols = N >> 8;
    const int row0 = (bid / cols) << 8;
    const int col0 = (bid % cols) << 8;

    const int t = threadIdx.x;
    const int w = t >> 6, l = t & 63;
    const int wr = w >> 2, wc = w & 3;      // 2 x 4 wave grid

    // ---- staging source pointers (lane-fixed), chunks 2w, 2w+1 ----
    // stage lane: r = c*16 + (l>>2), LDS linear (r, (l&3)*16B) holds
    // global elem k' = ((l&3) ^ ((r>>1)&3))*8 = ((l&3) ^ ((l>>3)&3))*8
    const int src_kelem = (((l & 3) ^ ((l >> 3) & 3)) << 3);
    const short* pA[2]; const short* pB[2];
    #pragma unroll
    for (int j = 0; j < 2; j++) {
        const int c = 2*w + j;
        const int rr = c*16 + (l >> 2);
        pA[j] = A  + (size_t)(row0 + rr) * K + src_kelem;
        pB[j] = Bt + (size_t)(col0 + rr) * K + src_kelem;
    }

    // stage part p (0=A_k0, 1=B_k0, 2=A_k1, 3=B_k1) of tile kt into buf
    auto STAGE = [&](int p, int ktile, int buf) {
        const int op = p & 1, kh = p >> 1;
        const int koff = ktile * 64 + kh * 32;
        const int reg = (buf*4 + op*2 + kh) * 8192;   // elements
        #pragma unroll
        for (int j = 0; j < 2; j++) {
            const short* g = (op ? pB[j] : pA[j]) + koff;
            short* d = (short*)lds + reg + (2*w + j) * 512;
            gload16(g, d);
        }
    };

    // ---- fragment read addressing (round-3-verified lane mapping + T2) ----
    // byte addr within region = r*64 + ((l>>4)*16 ^ ((r>>1)&3)<<4);
    // (r>>1)&3 == (l>>1)&3 for all frag rows (r = base16k + (l&15))
    const int axk = (((l >> 4) << 4) ^ (((l >> 1) & 3) << 4));

    bf16x8 a[4], b[4];
    f32x4 acc[8][4] = {};

    auto RD_B = [&](int buf, int kh) {
        const char* base = (const char*)lds + (buf*4 + 2 + kh) * 16384;
        #pragma unroll
        for (int i = 0; i < 4; i++) {
            const int c = wc*64 + i*16 + (l & 15);
            b[i] = *(const bf16x8*)(base + c*64 + axk);
        }
    };
    auto RD_A = [&](int buf, int kh, int mih) {
        const char* base = (const char*)lds + (buf*4 + kh) * 16384;
        #pragma unroll
        for (int i = 0; i < 4; i++) {
            const int r = wr*128 + (mih*4 + i)*16 + (l & 15);
            a[i] = *(const bf16x8*)(base + r*64 + axk);
        }
    };
    auto MF = [&](int mih) {
        __builtin_amdgcn_s_setprio(1);
        #pragma unroll
        for (int i = 0; i < 4; i++)
            #pragma unroll
            for (int ni = 0; ni < 4; ni++)
                acc[mih*4 + i][ni] = __builtin_amdgcn_mfma_f32_16x16x32_bf16(
                    a[i], b[ni], acc[mih*4 + i][ni], 0, 0, 0);
        __builtin_amdgcn_s_setprio(0);
    };

    // prologue: all 4 halves of tile 0
    STAGE(0, 0, 0); STAGE(1, 0, 0); STAGE(2, 0, 0); STAGE(3, 0, 0);

    const int NT = K >> 6;
    for (int kt2 = 0; kt2 + 1 < NT; ++kt2) {
        const int buf = kt2 & 1, nbuf = buf ^ 1, nt = kt2 + 1;
        // phase 0: (kh0, mi 0-3)
        STAGE(0, nt, nbuf);
        asm volatile("s_waitcnt vmcnt(6)" ::: "memory");
        block_barrier();
        RD_B(buf, 0); RD_A(buf, 0, 0);
        MF(0);
        block_barrier();
        // phase 1: (kh0, mi 4-7)
        RD_A(buf, 0, 1);
        STAGE(1, nt, nbuf);
        block_barrier();
        MF(1);
        block_barrier();
        // phase 2: (kh1, mi 0-3)
        STAGE(2, nt, nbuf);
        asm volatile("s_waitcnt vmcnt(6)" ::: "memory");
        block_barrier();
        RD_B(buf, 1); RD_A(buf, 1, 0);
        MF(0);
        block_barrier();
        // phase 3: (kh1, mi 4-7)
        RD_A(buf, 1, 1);
        STAGE(3, nt, nbuf);
        block_barrier();
        MF(1);
        block_barrier();
    }
    {   // last tile: no stages; drain 4 -> 0
        const int buf = (NT - 1) & 1;
        asm volatile("s_waitcnt vmcnt(4)" ::: "memory");
        block_barrier();
        RD_B(buf, 0); RD_A(buf, 0, 0);
        MF(0);
        block_barrier();
        RD_A(buf, 0, 1);
        block_barrier();
        MF(1);
        block_barrier();
        asm volatile("s_waitcnt vmcnt(0)" ::: "memory");
        block_barrier();
        RD_B(buf, 1); RD_A(buf, 1, 0);
        MF(0);
        block_barrier();
        RD_A(buf, 1, 1);
        MF(1);
    }

    // epilogue (C/D mapping: col = lane&15, row = (lane>>4)*4 + reg)
    const float alpha = (EPI == EPI_WO) ? alpha_p[0] : 0.0f;
    #pragma unroll
    for (int mi = 0; mi < 8; mi++) {
        const int rbase = row0 + wr*128 + mi*16 + ((l >> 4) << 2);
        #pragma unroll
        for (int ni = 0; ni < 4; ni++) {
            const int c = col0 + wc*64 + ni*16 + (l & 15);
            const float bc = bias[c];
            #pragma unroll
            for (int r = 0; r < 4; r++) {
                const int rr = rbase + r;
                const size_t idx = (size_t)rr * N + c;
                float val = acc[mi][ni][r] + bc;
                if (EPI == EPI_GELU) {
                    val = 0.5f * val * (1.0f + erff(val * 0.70710678118654752f));
                    ((__hip_bfloat16*)Cout)[idx] = __float2bfloat16(val);
                } else if (EPI == EPI_WO) {
                    ((float*)Cout)[idx] = xres[idx] + alpha * gate[rr] * val;
                } else if (EPI == EPI_RES) {
                    ((float*)Cout)[idx] = yres[idx] + val;
                } else {
                    ((float*)Cout)[idx] = val;
                }
            }
        }
    }
}

// ---------------------------------------------------------------------------
// Attention (fp32 math): block = (b, h, 256-row tile); lane owns one q row.
// top-5 online, softmax over 5, PV. Output bf16.
// ---------------------------------------------------------------------------
__global__ __launch_bounds__(256)
void attn_kernel(const float* __restrict__ qf, const float* __restrict__ kf,
                 const float* __restrict__ vf, const float* __restrict__ qinv,
                 const float* __restrict__ kinv, const float* __restrict__ msk,
                 const float* __restrict__ logit_scale,
                 __hip_bfloat16* __restrict__ out)
{
    __shared__ float k_lds[Tt][Dh + 4];
    __shared__ float v_lds[Tt][Dh + 4];
    __shared__ float kinv_s[Tt];
    __shared__ float msk_s[Tt];

    const int gid = blockIdx.x;
    const int b = gid >> 7;
    const int h = (gid >> 4) & 7;
    const int ntile = gid & 15;
    const int t = threadIdx.x;

    for (int idx = t; idx < Tt * Dh; idx += 256) {
        const int tt = idx >> 6, dd = idx & 63;
        k_lds[tt][dd] = kf[(size_t)(b * Tt + tt) * Cvd + h * Dh + dd];
        v_lds[tt][dd] = vf[(size_t)(b * Tt + tt) * Cvd + h * Dh + dd];
    }
    if (t < Tt) {
        kinv_s[t] = kinv[b * Tt + t];
        msk_s[t]  = msk[b * Tt + t];
    }
    __syncthreads();

    float ls = logit_scale[0];
    ls = fminf(fmaxf(ls, -2.0f), 2.0f);
    const float scale = expf(ls) * 0.125f;

    const int wave = t >> 6, lane = t & 63;
    const int row = b * Nv + ntile * 256 + wave * 64 + lane;

    float q[Dh];
    const float4* qp = (const float4*)(qf + (size_t)row * Cvd + h * Dh);
    #pragma unroll
    for (int i = 0; i < 16; i++) {
        const float4 x = qp[i];
        q[4*i] = x.x; q[4*i+1] = x.y; q[4*i+2] = x.z; q[4*i+3] = x.w;
    }
    const float qsc = qinv[row] * scale;

    float v0 = -INFINITY, v1 = -INFINITY, v2 = -INFINITY, v3 = -INFINITY, v4 = -INFINITY;
    int   i0 = 0, i1 = 0, i2 = 0, i3 = 0, i4 = 0;

    for (int tt = 0; tt < Tt; tt++) {
        float s = 0.0f;
        const float4* kp = (const float4*)&k_lds[tt][0];
        #pragma unroll
        for (int i = 0; i < 16; i++) {
            const float4 kx = kp[i];
            s += q[4*i] * kx.x + q[4*i+1] * kx.y + q[4*i+2] * kx.z + q[4*i+3] * kx.w;
        }
        s = s * qsc * kinv_s[tt];
        if (msk_s[tt] != 0.0f) s = -INFINITY;

        const bool c0 = s > v0, c1 = s > v1, c2 = s > v2, c3 = s > v3, c4 = s > v4;
        const float nv0 = c0 ? s : v0;               const int ni0 = c0 ? tt : i0;
        const float nv1 = c1 ? (c0 ? v0 : s) : v1;   const int ni1 = c1 ? (c0 ? i0 : tt) : i1;
        const float nv2 = c2 ? (c1 ? v1 : s) : v2;   const int ni2 = c2 ? (c1 ? i1 : tt) : i2;
        const float nv3 = c3 ? (c2 ? v2 : s) : v3;   const int ni3 = c3 ? (c2 ? i2 : tt) : i3;
        const float nv4 = c4 ? (c3 ? v3 : s) : v4;   const int ni4 = c4 ? (c3 ? i3 : tt) : i4;
        v0 = nv0; v1 = nv1; v2 = nv2; v3 = nv3; v4 = nv4;
        i0 = ni0; i1 = ni1; i2 = ni2; i3 = ni3; i4 = ni4;
    }

    const float m = v0;
    const float e0 = __expf(v0 - m), e1 = __expf(v1 - m), e2 = __expf(v2 - m),
                e3 = __expf(v3 - m), e4 = __expf(v4 - m);
    const float inv = 1.0f / (e0 + e1 + e2 + e3 + e4);
    const float w0 = e0 * inv, w1 = e1 * inv, w2 = e2 * inv, w3 = e3 * inv, w4 = e4 * inv;

    __hip_bfloat16* op = out + (size_t)row * Cvd + h * Dh;
    #pragma unroll
    for (int i = 0; i < 16; i++) {
        const float4 p0 = *(const float4*)&v_lds[i0][4*i];
        const float4 p1 = *(const float4*)&v_lds[i1][4*i];
        const float4 p2 = *(const float4*)&v_lds[i2][4*i];
        const float4 p3 = *(const float4*)&v_lds[i3][4*i];
        const float4 p4 = *(const float4*)&v_lds[i4][4*i];
        float4 a;
        a.x = w0*p0.x + w1*p1.x + w2*p2.x + w3*p3.x + w4*p4.x;
        a.y = w0*p0.y + w1*p1.y + w2*p2.y + w3*p3.y + w4*p4.y;
        a.z = w0*p0.z + w1*p1.z + w2*p2.z + w3*p3.z + w4*p4.z;
        a.w = w0*p0.w + w1*p1.w + w2*p2.w + w3*p3.w + w4*p4.w;
        __hip_bfloat162 h0, h1;
        h0.x = __float2bfloat16(a.x); h0.y = __float2bfloat16(a.y);
        h1.x = __float2bfloat16(a.z); h1.y = __float2bfloat16(a.w);
        *(__hip_bfloat162*)&op[4*i]     = h0;
        *(__hip_bfloat162*)&op[4*i + 2] = h1;
    }
}

// ---------------------------------------------------------------------------
extern "C" void kernel_launch(void* const* d_in, const int* in_sizes, int n_in,
                              void* d_out, int out_size, void* d_ws, size_t ws_size,
                              hipStream_t stream)
{
    const float* visual = (const float*)d_in[0];
    const float* text   = (const float*)d_in[1];
    const float* n1w = (const float*)d_in[2];
    const float* n1b = (const float*)d_in[3];
    const float* Wq  = (const float*)d_in[4];
    const float* bq  = (const float*)d_in[5];
    const float* Wk  = (const float*)d_in[6];
    const float* bk  = (const float*)d_in[7];
    const float* Wv  = (const float*)d_in[8];
    const float* bv  = (const float*)d_in[9];
    const float* Wo  = (const float*)d_in[10];
    const float* bo  = (const float*)d_in[11];
    const float* gw  = (const float*)d_in[12];
    const float* gb  = (const float*)d_in[13];
    const float* n2w = (const float*)d_in[14];
    const float* n2b = (const float*)d_in[15];
    const float* w1  = (const float*)d_in[16];
    const float* b1  = (const float*)d_in[17];
    const float* w2  = (const float*)d_in[18];
    const float* b2  = (const float*)d_in[19];
    const float* lsc = (const float*)d_in[20];
    const float* alp = (const float*)d_in[21];

    float* out = (float*)d_out;
    char*  w8  = (char*)d_ws;

    // workspace (byte offsets, aliased by lifetime):
    float*          qfull  = (float*)(w8 + 0);
    float*          ypre   = (float*)(w8 + 67108864);
    __hip_bfloat16* hidden = (__hip_bfloat16*)(w8 + 0);
    __hip_bfloat16* xbf    = (__hip_bfloat16*)(w8 + 134217728);  // also attnout, y_bf16
    float*          kf     = (float*)(w8 + 167772160);
    float*          vf     = (float*)(w8 + 169033728);
    float*          qinv   = (float*)(w8 + 170295296);
    float*          kinv   = (float*)(w8 + 170426368);
    float*          mskp   = (float*)(w8 + 170428832);
    float*          gate   = (float*)(w8 + 170431296);
    __hip_bfloat16* WqT    = (__hip_bfloat16*)(w8 + 170562368);
    __hip_bfloat16* WoT    = (__hip_bfloat16*)(w8 + 171086656);
    __hip_bfloat16* w1T    = (__hip_bfloat16*)(w8 + 171610944);
    __hip_bfloat16* w2T    = (__hip_bfloat16*)(w8 + 173708096);

    // 0. weights -> bf16 transposed [N,K]
    wtrans_kernel<<<dim3(16, 16), dim3(256), 0, stream>>>(Wq, WqT, 512, 512);
    wtrans_kernel<<<dim3(16, 16), dim3(256), 0, stream>>>(Wo, WoT, 512, 512);
    wtrans_kernel<<<dim3(64, 16), dim3(256), 0, stream>>>(w1, w1T, 512, 2048);
    wtrans_kernel<<<dim3(16, 64), dim3(256), 0, stream>>>(w2, w2T, 2048, 512);

    // 1. LN1: x -> d_out (f32) + xbf (bf16); gate logits
    ln_kernel<true><<<dim3(MROWS), dim3(128), 0, stream>>>(
        visual, n1w, n1b, out, xbf, gw, gb, gate);

    // 2. q_full = x @ Wq + bq  (bf16 MFMA, f32 out); grid (M/256)*(N/256)
    bgemm8_kernel<EPI_NONE><<<dim3(256), dim3(512), 0, stream>>>(
        xbf, WqT, bq, qfull, MROWS, 512, 512, nullptr, nullptr, nullptr, nullptr);

    // 3. k_full / v_full (fp32, tiny M=616)
    gemm32_kernel<<<dim3(8, 10), dim3(256), 0, stream>>>(
        text, 512, Wk, 512, bk, kf, 512, KTROWS, 512);
    gemm32_kernel<<<dim3(8, 10), dim3(256), 0, stream>>>(
        text, 512, Wv, 512, bv, vf, 512, KTROWS, 512);

    // 4. norms + pad mask
    rownorm_kernel<<<dim3(MROWS), dim3(64), 0, stream>>>(qfull, qinv);
    knorm_mask_kernel<<<dim3(KTROWS), dim3(64), 0, stream>>>(kf, text, kinv, mskp);

    // 5. attention -> attnout bf16 (reuses xbf buffer; x_bf16 dead)
    attn_kernel<<<dim3(1024), dim3(256), 0, stream>>>(
        qfull, kf, vf, qinv, kinv, mskp, lsc, xbf);

    // 6. y_pre = x + alpha*gate*(attnout @ Wo + bo)
    bgemm8_kernel<EPI_WO><<<dim3(256), dim3(512), 0, stream>>>(
        xbf, WoT, bo, ypre, MROWS, 512, 512, out, gate, alp, nullptr);

    // 7. y = LN2(y_pre) -> d_out (f32, residual for FFN2) + y_bf16 (reuses xbf)
    ln_kernel<false><<<dim3(MROWS), dim3(128), 0, stream>>>(
        ypre, n2w, n2b, out, xbf, nullptr, nullptr, nullptr);

    // 8. hidden = gelu(y @ w1 + b1) -> bf16 (aliases qfull+ypre, both dead)
    bgemm8_kernel<EPI_GELU><<<dim3(1024), dim3(512), 0, stream>>>(
        xbf, w1T, b1, hidden, MROWS, 2048, 512, nullptr, nullptr, nullptr, nullptr);

    // 9. out = y + hidden @ w2 + b2 (in-place on d_out)
    bgemm8_kernel<EPI_RES><<<dim3(256), dim3(512), 0, stream>>>(
        hidden, w2T, b2, out, MROWS, 512, 2048, nullptr, nullptr, nullptr, out);
}